// Round 10
// baseline (214.356 us; speedup 1.0000x reference)
//
#include <hip/hip_runtime.h>
#include <hip/hip_bf16.h>

// B=4, N=1024, C=768, H=12, D=64, SCALE=1/8. Inputs fp32, output fp32.
// Internal math bf16 MFMA. fp32->bf16 pre-convert enables global_load_lds(16B).
//
// GLOBAL K-MAJOR TILED LAYOUT for all GEMM operands (Xc, Wqc, Wpc, o_ws):
//   [G][kt][kslot][r][ke]  where G = row/16, r = row%16, kt = k/32,
//   kslot = (k%32)/8, ke = k%8.  One (G,kt) block = 512 elems = 1 KB.
// Staging reads a CONTIGUOUS 1 KB per global_load_lds (base + lane*16B),
// LDS stays linear, MFMA fragment reads are group_base + lane*16B ->
// sequential 1 KB stream, ZERO bank conflicts (verified round 7).

typedef __bf16 bf16x8 __attribute__((ext_vector_type(8)));
typedef __bf16 bf16x4 __attribute__((ext_vector_type(4)));
typedef float  f32x4  __attribute__((ext_vector_type(4)));

__device__ __forceinline__ bf16x8 cvt8(const float* p) {
    f32x4 f0 = *(const f32x4*)p;
    f32x4 f1 = *(const f32x4*)(p + 4);
    bf16x8 r;
    r[0] = (__bf16)f0[0]; r[1] = (__bf16)f0[1]; r[2] = (__bf16)f0[2]; r[3] = (__bf16)f0[3];
    r[4] = (__bf16)f1[0]; r[5] = (__bf16)f1[1]; r[6] = (__bf16)f1[2]; r[7] = (__bf16)f1[3];
    return r;
}

__device__ __forceinline__ void async16(const __bf16* g, __bf16* l) {
    __builtin_amdgcn_global_load_lds(
        (const __attribute__((address_space(1))) void*)g,
        (__attribute__((address_space(3))) void*)l, 16, 0, 0);
}

// ---------------------------------------------------------------------------
// Tiled convert via LDS transpose (round-8 version, unchanged).
// ---------------------------------------------------------------------------
__global__ __launch_bounds__(256)
void cvt4_k(const float* __restrict__ x1, const float* __restrict__ x2,
            const float* __restrict__ wq, const float* __restrict__ wp,
            __bf16* __restrict__ xc, __bf16* __restrict__ wqc,
            __bf16* __restrict__ wpc)
{
    __shared__ __bf16 L[16][776];        // +8 pad
    const int bid = blockIdx.x, t = threadIdx.x;
    const float* src; __bf16* dst; int G;
    if (bid < 256)      { src = x1; dst = xc;            G = bid; }
    else if (bid < 512) { src = x2; dst = xc + 3145728;  G = bid - 256; }
    else if (bid < 656) { src = wq; dst = wqc;           G = bid - 512; }
    else                { src = wp; dst = wpc;           G = bid - 656; }

    const float* sb = src + (size_t)G * 16 * 768;
#pragma unroll
    for (int k = 0; k < 6; k++) {
        int iv = k * 256 + t;            // 0..1535 (f32x8 runs)
        int row = iv / 96, c8 = iv % 96;
        *(bf16x8*)&L[row][c8 * 8] = cvt8(sb + row * 768 + c8 * 8);
    }
    __syncthreads();
    __bf16* db = dst + (size_t)G * 12288;   // G-stripe: 24 kt x 512, contiguous
#pragma unroll
    for (int k = 0; k < 6; k++) {
        int j = k * 256 + t;             // 0..1535 (bf16x8 runs)
        int r = j & 15, ks = (j >> 4) & 3, kt = j >> 6;
        *(bf16x8*)(db + (size_t)j * 8) = *(const bf16x8*)&L[r][kt * 32 + ks * 8];
    }
}

// legacy scalar tiled convert (only used when ws too small for fused Wp path)
__global__ __launch_bounds__(256)
void cvt_kt(const float* __restrict__ src, __bf16* __restrict__ dst, int nrun) {
    int j = blockIdx.x * 256 + threadIdx.x;
    if (j >= nrun) return;
    const int r  = j & 15;
    const int ks = (j >> 4) & 3;
    const int t2 = j >> 6;
    const int kt = t2 % 24;
    const int G  = t2 / 24;
    *(bf16x8*)(dst + (size_t)j * 8) =
        cvt8(src + (size_t)(G * 16 + r) * 768 + kt * 32 + ks * 8);
}

// ---------------------------------------------------------------------------
// QKV GEMM, 128x128 tile, BK=32, 3-buffer counted-vmcnt pipeline on TILED
// operands (round-7 structure, 56.4us, 0 bank conflicts). Unchanged.
// ---------------------------------------------------------------------------
__global__ __launch_bounds__(256)
void gemm_qkv_s(const __bf16* __restrict__ Xc, const __bf16* __restrict__ Wq,
                const float* __restrict__ bias,
                __bf16* __restrict__ qo, __bf16* __restrict__ ko,
                __bf16* __restrict__ vo)
{
    __shared__ __bf16 As[3][128 * 32];   // 24 KB (8 groups x 512 elems)
    __shared__ __bf16 Bs[3][128 * 32];   // 24 KB

    const int t = threadIdx.x, w = t >> 6, lane = t & 63;
    const int l15 = lane & 15, quad = lane >> 4;
    const int wm = w >> 1, wn = w & 1;

    const int bid  = blockIdx.x;          // 0..1151
    const int xcd  = bid & 7;
    const int i6   = bid >> 3;            // 0..143
    const int pair = i6 / 18;             // 0..7
    const int gx   = i6 - pair * 18;      // 0..17
    const int p    = xcd * 8 + pair;      // 0..63
    const int gy   = p & 31;
    const int st   = p >> 5;

    const __bf16* Ab = Xc + (size_t)st * 3145728 + (size_t)(gy * 8) * 24 * 512;
    const __bf16* Bb = Wq + (size_t)(gx * 8) * 24 * 512;

    f32x4 acc[4][4];
#pragma unroll
    for (int mi = 0; mi < 4; mi++)
#pragma unroll
        for (int ni = 0; ni < 4; ni++) acc[mi][ni] = f32x4{0.f, 0.f, 0.f, 0.f};

    const int ga0 = w * 2, ga1 = w * 2 + 1;     // this wave's groups

#define QSTAGE(BUF, KT)                                                          \
    do {                                                                         \
        async16(Ab + ((size_t)ga0 * 24 + (KT)) * 512 + lane * 8,                 \
                &As[BUF][ga0 * 512 + lane * 8]);                                 \
        async16(Ab + ((size_t)ga1 * 24 + (KT)) * 512 + lane * 8,                 \
                &As[BUF][ga1 * 512 + lane * 8]);                                 \
        async16(Bb + ((size_t)ga0 * 24 + (KT)) * 512 + lane * 8,                 \
                &Bs[BUF][ga0 * 512 + lane * 8]);                                 \
        async16(Bb + ((size_t)ga1 * 24 + (KT)) * 512 + lane * 8,                 \
                &Bs[BUF][ga1 * 512 + lane * 8]);                                 \
    } while (0)

    QSTAGE(0, 0);

#pragma unroll 3
    for (int kt = 0; kt < 24; kt++) {
        const int cb = kt % 3;
        if (kt < 23) {
            QSTAGE((kt + 1) % 3, kt + 1);
            asm volatile("s_waitcnt vmcnt(4)" ::: "memory");  // kt landed; kt+1 in flight
        } else {
            asm volatile("s_waitcnt vmcnt(0)" ::: "memory");  // tail drain
        }
        __builtin_amdgcn_s_barrier();
        __builtin_amdgcn_sched_barrier(0);

        bf16x8 af[4], bfr[4];
#pragma unroll
        for (int mi = 0; mi < 4; mi++)
            af[mi] = *(const bf16x8*)&As[cb][(wm * 4 + mi) * 512 + lane * 8];
#pragma unroll
        for (int ni = 0; ni < 4; ni++)
            bfr[ni] = *(const bf16x8*)&Bs[cb][(wn * 4 + ni) * 512 + lane * 8];
#pragma unroll
        for (int mi = 0; mi < 4; mi++)
#pragma unroll
            for (int ni = 0; ni < 4; ni++)
                acc[mi][ni] = __builtin_amdgcn_mfma_f32_16x16x32_bf16(af[mi], bfr[ni], acc[mi][ni], 0, 0, 0);
    }
#undef QSTAGE

    const int which = (gx * 128) / 768;   // uniform per block (tile never spans)

    if (which == 2) {
#pragma unroll
        for (int ni = 0; ni < 4; ni++) {
            int j = gx * 128 + wn * 64 + ni * 16 + l15;
            int c = j - 1536;
            int h = c >> 6, d = c & 63;
            float bj = bias[j];
#pragma unroll
            for (int mi = 0; mi < 4; mi++) {
                int row0 = gy * 128 + wm * 64 + mi * 16 + quad * 4;
                int b = row0 >> 10, tok0 = row0 & 1023;
                bf16x4 pv;
#pragma unroll
                for (int r = 0; r < 4; r++) pv[r] = (__bf16)(acc[mi][ni][r] + bj);
                *(bf16x4*)&vo[((size_t)((st * 4 + b) * 12 + h) * 64 + d) * 1024 + tok0] = pv;
            }
        }
    } else {
#pragma unroll
        for (int ni = 0; ni < 4; ni++) {
            int j     = gx * 128 + wn * 64 + ni * 16 + l15;   // 0..1535
            int c     = j - which * 768;
            int h = c >> 6, d = c & 63;
            float bj  = bias[j];
#pragma unroll
            for (int mi = 0; mi < 4; mi++) {
#pragma unroll
                for (int r = 0; r < 4; r++) {
                    int row = gy * 128 + wm * 64 + mi * 16 + quad * 4 + r;
                    int b = row >> 10, tok = row & 1023;
                    float val = acc[mi][ni][r] + bj;
                    if (which == 0)
                        qo[((size_t)((st * 4 + b) * 12 + h) * 1024 + tok) * 64 + d] = (__bf16)(val * 0.125f);
                    else
                        ko[((size_t)((st * 4 + b) * 12 + h) * 1024 + tok) * 64 + d] = (__bf16)val;
                }
            }
        }
    }
}

// ---------------------------------------------------------------------------
// proj GEMM, 64x128 tile, BK=32, 3-buffer counted-vmcnt pipeline, TILED
// operands, grid 6x128 = 768 = 3/CU balanced (round-8 version, unchanged).
// ---------------------------------------------------------------------------
__global__ __launch_bounds__(256)
void gemm_proj(const __bf16* __restrict__ A, const __bf16* __restrict__ Wp,
               const float* __restrict__ bias, float* __restrict__ out)
{
    __shared__ __bf16 As[3][64 * 32];    // 4 KB per buf
    __shared__ __bf16 Bs[3][128 * 32];   // 8 KB per buf

    const int t = threadIdx.x, w = t >> 6, lane = t & 63;
    const int l15 = lane & 15, quad = lane >> 4;
    const int wm = w >> 1, wn = w & 1;
    const int gx = blockIdx.x, gy = blockIdx.y;   // 6 x 128

    const __bf16* Ab = A  + (size_t)(gy * 4) * 24 * 512;
    const __bf16* Bb = Wp + (size_t)(gx * 8) * 24 * 512;

    f32x4 acc[2][4];
#pragma unroll
    for (int mi = 0; mi < 2; mi++)
#pragma unroll
        for (int ni = 0; ni < 4; ni++) acc[mi][ni] = f32x4{0.f, 0.f, 0.f, 0.f};

#define PSTAGE(BUF, KT)                                                          \
    do {                                                                         \
        async16(Ab + ((size_t)w * 24 + (KT)) * 512 + lane * 8,                   \
                &As[BUF][w * 512 + lane * 8]);                                   \
        async16(Bb + ((size_t)(w * 2) * 24 + (KT)) * 512 + lane * 8,             \
                &Bs[BUF][(w * 2) * 512 + lane * 8]);                             \
        async16(Bb + ((size_t)(w * 2 + 1) * 24 + (KT)) * 512 + lane * 8,         \
                &Bs[BUF][(w * 2 + 1) * 512 + lane * 8]);                         \
    } while (0)

    PSTAGE(0, 0);

#pragma unroll 3
    for (int kt = 0; kt < 24; kt++) {
        const int cb = kt % 3;
        if (kt < 23) {
            PSTAGE((kt + 1) % 3, kt + 1);
            asm volatile("s_waitcnt vmcnt(3)" ::: "memory");
        } else {
            asm volatile("s_waitcnt vmcnt(0)" ::: "memory");
        }
        __builtin_amdgcn_s_barrier();
        __builtin_amdgcn_sched_barrier(0);

        bf16x8 af[2], bfr[4];
#pragma unroll
        for (int mi = 0; mi < 2; mi++)
            af[mi] = *(const bf16x8*)&As[cb][(wm * 2 + mi) * 512 + lane * 8];
#pragma unroll
        for (int ni = 0; ni < 4; ni++)
            bfr[ni] = *(const bf16x8*)&Bs[cb][(wn * 4 + ni) * 512 + lane * 8];
#pragma unroll
        for (int mi = 0; mi < 2; mi++)
#pragma unroll
            for (int ni = 0; ni < 4; ni++)
                acc[mi][ni] = __builtin_amdgcn_mfma_f32_16x16x32_bf16(af[mi], bfr[ni], acc[mi][ni], 0, 0, 0);
    }
#undef PSTAGE

#pragma unroll
    for (int ni = 0; ni < 4; ni++) {
        int col  = gx * 128 + wn * 64 + ni * 16 + l15;
        float bj = bias[col];
#pragma unroll
        for (int mi = 0; mi < 2; mi++)
#pragma unroll
            for (int r = 0; r < 4; r++) {
                int row = gy * 64 + (wm * 2 + mi) * 16 + quad * 4 + r;  // 0..8191
                out[(size_t)row * 768 + col] = acc[mi][ni][r] + bj;
            }
    }
}

// ---------------------------------------------------------------------------
// Dual-stream flash attention v3: IN-BLOCK K-SPLIT for occupancy.
// 4 waves/block (256 thr): pair p = w>>1 owns keys [p*512, p*512+512);
// qsub = w&1 owns q-rows [qsub*32 .. +32) as 2 register q-sets. Every wave:
// 16 iters of 32-key tiles, single-buffered pair-private K/V staging
// (stage -> vmcnt(0) -> barrier -> compute -> barrier). R1 proved prefetch
// hiding is ~0 here; the win is 6 -> 12 waves/CU (1.5 -> 3 waves/SIMD) and
// 32 -> 16 serial iters. Post-loop: p=1 waves fold accO/lsum into p=0 via
// LDS region aliased over the dead K/V buffers (33.8 KB < 51.2 KB).
// LDS 51.2 KB -> 3 blocks/CU; grid 768 = 3*256 exactly balanced.
// Math identical: softmax numerators are linear in the key partition;
// accO/lsum folded before the final normalization.
// ---------------------------------------------------------------------------
__global__ __launch_bounds__(256, 3)
void attn_k(const __bf16* __restrict__ qws, const __bf16* __restrict__ kws,
            const __bf16* __restrict__ vws, __bf16* __restrict__ ows)
{
    __shared__ __align__(16) char SMEM[51200];
    __bf16* KF  = (__bf16*)SMEM;             // K frags [p][s][kk][mi2]*512 (16 KB)
    __bf16* VF  = (__bf16*)(SMEM + 16384);   // V frags [p][s][mi4]*512    (16 KB)
    __bf16* PS  = (__bf16*)(SMEM + 32768);   // Ps [w][set]*1152           (18.4 KB)
    float*  RED = (float*)SMEM;              // post-loop fold (aliases KF/VF/PS)

    const int g  = blockIdx.x;
    const int qt = g / 48;              // 0..15
    const int bh = g % 48;              // 0..47
    const int b = bh / 12, h = bh % 12;
    const int t = threadIdx.x, w = t >> 6, lane = t & 63;
    const int l15 = lane & 15, quad = lane >> 4;
    const int p = w >> 1, qsub = w & 1;

    const size_t head_off = (size_t)bh * 65536;          // 1024*64
    const size_t ss       = (size_t)48 * 65536;          // stream stride

    // Q: this wave's 32 rows (2 sets x 2 streams x 2 kk -> 8 bf16x8)
    bf16x8 qf[2][2][2];
#pragma unroll
    for (int set = 0; set < 2; set++)
#pragma unroll
        for (int s = 0; s < 2; s++)
#pragma unroll
            for (int kk = 0; kk < 2; kk++)
                qf[set][s][kk] = *(const bf16x8*)(qws + s * ss + head_off
                    + (size_t)(qt * 64 + qsub * 32 + set * 16 + l15) * 64 + kk * 32 + quad * 8);

    float lsum[2] = {0.f, 0.f};
    f32x4 accO[2][2][4];
#pragma unroll
    for (int set = 0; set < 2; set++)
#pragma unroll
        for (int s = 0; s < 2; s++)
#pragma unroll
            for (int mi = 0; mi < 4; mi++) accO[set][s][mi] = f32x4{0.f, 0.f, 0.f, 0.f};

    const __bf16* kbase = kws + head_off;
    const __bf16* vbase = vws + head_off;

    for (int kt = 0; kt < 16; kt++) {
        const int keyb = p * 512 + kt * 32;

        // ---- stage this pair's K/V tile (single buffer, pair-private)
        if (qsub == 0) {
#pragma unroll
            for (int i = 0; i < 8; i++) {
                const int s = i >> 2, kk = (i >> 1) & 1, mi = i & 1;
                async16(kbase + s * ss + (size_t)(keyb + mi * 16 + l15) * 64
                            + kk * 32 + quad * 8,
                        KF + (size_t)(p * 8 + s * 4 + kk * 2 + mi) * 512 + lane * 8);
            }
        } else {
#pragma unroll
            for (int i = 0; i < 8; i++) {
                const int s = i >> 2, mi = i & 3;
                async16(vbase + s * ss + (size_t)(mi * 16 + l15) * 1024
                            + keyb + quad * 8,
                        VF + (size_t)(p * 8 + s * 4 + mi) * 512 + lane * 8);
            }
        }
        asm volatile("s_waitcnt vmcnt(0)" ::: "memory");
        __builtin_amdgcn_s_barrier();
        __builtin_amdgcn_sched_barrier(0);

        // ---- QK^T: S = S1 + S2 in one accumulation chain
        f32x4 accS[2][2];
#pragma unroll
        for (int set = 0; set < 2; set++)
#pragma unroll
            for (int mi = 0; mi < 2; mi++) accS[set][mi] = f32x4{0.f, 0.f, 0.f, 0.f};
        __builtin_amdgcn_s_setprio(1);
#pragma unroll
        for (int s = 0; s < 2; s++)
#pragma unroll
            for (int kk = 0; kk < 2; kk++) {
                bf16x8 kf0 = *(const bf16x8*)&KF[(size_t)(p * 8 + s * 4 + kk * 2 + 0) * 512 + lane * 8];
                bf16x8 kf1 = *(const bf16x8*)&KF[(size_t)(p * 8 + s * 4 + kk * 2 + 1) * 512 + lane * 8];
#pragma unroll
                for (int set = 0; set < 2; set++) {
                    accS[set][0] = __builtin_amdgcn_mfma_f32_16x16x32_bf16(kf0, qf[set][s][kk], accS[set][0], 0, 0, 0);
                    accS[set][1] = __builtin_amdgcn_mfma_f32_16x16x32_bf16(kf1, qf[set][s][kk], accS[set][1], 0, 0, 0);
                }
            }
        __builtin_amdgcn_s_setprio(0);

        // ---- softmax numerator (no-max; scores bounded)
#pragma unroll
        for (int set = 0; set < 2; set++) {
            float rs = 0.f;
#pragma unroll
            for (int mi = 0; mi < 2; mi++) {
                bf16x4 pk;
#pragma unroll
                for (int r = 0; r < 4; r++) {
                    float pv = __expf(accS[set][mi][r]);
                    pk[r] = (__bf16)pv;
                    rs += pv;
                }
                *(bf16x4*)&PS[(size_t)(w * 2 + set) * 1152 + l15 * 72 + mi * 16 + quad * 4] = pk;
            }
            lsum[set] += rs;
        }

        // ---- PV (O^T = V^T @ P^T); each vf read feeds both q-sets
        bf16x8 pa0 = *(const bf16x8*)&PS[(size_t)(w * 2 + 0) * 1152 + l15 * 72 + quad * 8];
        bf16x8 pa1 = *(const bf16x8*)&PS[(size_t)(w * 2 + 1) * 1152 + l15 * 72 + quad * 8];
        __builtin_amdgcn_s_setprio(1);
#pragma unroll
        for (int s = 0; s < 2; s++)
#pragma unroll
            for (int mi = 0; mi < 4; mi++) {
                bf16x8 vf = *(const bf16x8*)&VF[(size_t)(p * 8 + s * 4 + mi) * 512 + lane * 8];
                accO[0][s][mi] = __builtin_amdgcn_mfma_f32_16x16x32_bf16(vf, pa0, accO[0][s][mi], 0, 0, 0);
                accO[1][s][mi] = __builtin_amdgcn_mfma_f32_16x16x32_bf16(vf, pa1, accO[1][s][mi], 0, 0, 0);
            }
        __builtin_amdgcn_s_setprio(0);

        // WAR barrier: next iter's stage overwrites this (single) buffer
        __builtin_amdgcn_s_barrier();
    }

    // ---- fold pair p=1 into p=0 (RED aliases dead K/V/Ps; sync via
    // __syncthreads so LDS writes drain before the cross-wave read)
    __syncthreads();
    if (p == 1) {
        float* R = RED + (size_t)(qsub * 64 + lane) * 66;
        int idx = 0;
#pragma unroll
        for (int set = 0; set < 2; set++)
#pragma unroll
            for (int s = 0; s < 2; s++)
#pragma unroll
                for (int mi = 0; mi < 4; mi++)
#pragma unroll
                    for (int r = 0; r < 4; r++) R[idx++] = accO[set][s][mi][r];
        R[64] = lsum[0];
        R[65] = lsum[1];
    }
    __syncthreads();
    if (p == 1) return;

    {
        const float* R = RED + (size_t)(qsub * 64 + lane) * 66;
        int idx = 0;
#pragma unroll
        for (int set = 0; set < 2; set++)
#pragma unroll
            for (int s = 0; s < 2; s++)
#pragma unroll
                for (int mi = 0; mi < 4; mi++)
#pragma unroll
                    for (int r = 0; r < 4; r++) accO[set][s][mi][r] += R[idx++];
        lsum[0] += R[64];
        lsum[1] += R[65];
    }

#pragma unroll
    for (int set = 0; set < 2; set++) {
        float l = lsum[set];
        l += __shfl_xor(l, 16);
        l += __shfl_xor(l, 32);
        float il = 1.f / l;

        const int tok = qt * 64 + qsub * 32 + set * 16 + l15;
#pragma unroll
        for (int s = 0; s < 2; s++)
#pragma unroll
            for (int mi = 0; mi < 4; mi++) {
                bf16x4 ov;
#pragma unroll
                for (int r = 0; r < 4; r++) ov[r] = (__bf16)(accO[set][s][mi][r] * il);
                const int row = (s * 4 + b) * 1024 + tok;
                const int c   = h * 64 + mi * 16 + quad * 4;
                const size_t off = ((size_t)(row >> 4) * 24 + (c >> 5)) * 512
                                 + ((c >> 3) & 3) * 128 + (row & 15) * 8 + (c & 7);
                *(bf16x4*)&ows[off] = ov;
            }
    }
}

// ---------------------------------------------------------------------------
extern "C" void kernel_launch(void* const* d_in, const int* in_sizes, int n_in,
                              void* d_out, int out_size, void* d_ws, size_t ws_size,
                              hipStream_t stream)
{
    const float* x1    = (const float*)d_in[0];
    const float* x2    = (const float*)d_in[1];
    const float* Wqkv  = (const float*)d_in[2];
    const float* bqkv  = (const float*)d_in[3];
    const float* Wproj = (const float*)d_in[4];
    const float* bproj = (const float*)d_in[5];
    float* out = (float*)d_out;

    const size_t qkv_elems = (size_t)2 * 4 * 12 * 1024 * 64;   // 6,291,456
    __bf16* q_ws = (__bf16*)d_ws;
    __bf16* k_ws = q_ws + qkv_elems;
    __bf16* v_ws = k_ws + qkv_elems;
    __bf16* pool = v_ws + qkv_elems;
    __bf16* o_ws = pool;                // 8192*768 tiled (attn out)
    __bf16* Wqc  = pool + 3145728;      // 2304*768 tiled (dead after QKV GEMM)
    __bf16* Xc   = (__bf16*)d_out;      // x1c | x2c tiled (scratch in out buf)

    const bool big = ws_size >= (size_t)(4 * qkv_elems + 589824) * sizeof(__bf16);
    __bf16* Wpc = big ? (pool + qkv_elems)   // past proven footprint
                      : q_ws;                // legacy: q dead after attn

    // 1) fused fp32->bf16 tiled converts via LDS transpose
    cvt4_k<<<big ? 704 : 656, 256, 0, stream>>>(x1, x2, Wqkv, Wproj, Xc, Wqc, Wpc);
    // 2) QKV GEMM, tiled operands, XCD-ownership swizzle, 3-buf counted-vmcnt
    gemm_qkv_s<<<1152, 256, 0, stream>>>(Xc, Wqc, bqkv, q_ws, k_ws, v_ws);
    // 3) attention v3: in-block K-split, 4 waves, 12 waves/CU
    attn_k<<<768, 256, 0, stream>>>(q_ws, k_ws, v_ws, o_ws);
    // 4) legacy tiled proj weight convert only if ws too small
    if (!big) cvt_kt<<<288, 256, 0, stream>>>(Wproj, Wpc, 73728);
    // 5) proj GEMM, 64x128 tiles, grid 6x128 = 768 = 3/CU balanced
    gemm_proj<<<dim3(6, 128), 256, 0, stream>>>(o_ws, Wpc, bproj, out);
}